// Round 2
// baseline (58.425 us; speedup 1.0000x reference)
//
#include <hip/hip_runtime.h>
#include <math.h>

// Radon forward, exact reference semantics (rotated-lattice bilinear gather).
//
// Round-8 changes vs round 7 (49.5 us total; tile3 45.3 us, VALUBusy 42%,
// Occupancy 42%, LDS conflicts 8.80M cyc -- identical to round 6!):
//  * TS2 84 -> 80 (multiple of 16). Tile cells are 8 B so bank-pair =
//    rel mod 16; with row stride % 16 == 0 the ty-drift term vanishes from
//    the bank residue and the per-lane walk is tx-only (step ~cos in
//    [0.71,1]) -> <=2-4-way for ALL angles. TS2=84 had resonances
//    (84*s - c ~= 16m at theta ~= 11.7/23/35.7 deg -> 16-32-way).
//    Capacity: cols <= 74 < 80, rows <= 75 < 76, nchunk <= 47 <= 48.
//  * T14 async-STAGE pipeline: subtile k+1 is loaded into registers
//    (6 x 16B/lane, issued BEFORE gather of subtile k), ds_write'd after
//    the post-gather barrier. L2 latency (~200-500 cyc) hides under the
//    gather instead of a dead vmcnt(0) drain. Single 48 KiB buffer kept
//    -> 3 blocks/CU; __launch_bounds__(512,6) pins VGPR <= 85.
//  * Prologue subtile still staged via global_load_lds (exposed once).

#define G       363
#define NT      180
#define PADB    53
#define STEP    (2.0f / 362.0f)
#define DEG2RAD 0.017453292519943295f

#define TS2     80          // tile row length (f32x2 cells), MULTIPLE OF 16
#define TROWS   76          // max tile rows
#define NCHK    48          // max staging chunks (128 cells each)
#define NTILE   (NCHK * 128)   // 6144 cells = 49,152 B -> 3 blocks/CU
#define NJB     6
#define CW      262         // canvas cols
#define CH      260         // canvas rows  (image interior at [3..258]x[3..258])
#define NTUPLE  (90 * 6 * 12)

typedef __attribute__((ext_vector_type(2))) float f32x2;
typedef __attribute__((ext_vector_type(4))) float f32x4;

#define GLOAD16(gp, lp) __builtin_amdgcn_global_load_lds(                     \
    (const __attribute__((address_space(1))) void*)(gp),                      \
    (__attribute__((address_space(3))) void*)(lp), 16, 0, 0)

// ---------------- fallback gather kernel (known-good, round 1) -------------
__global__ __launch_bounds__(256) void radon_fwd(
    const float* __restrict__ x, const int* __restrict__ theta,
    float* __restrict__ out)
{
    const int t = blockIdx.x / NJB, jb = blockIdx.x % NJB;
    const int jl = threadIdx.x, chunk = threadIdx.y;
    const int j = jb * 64 + jl;
    const float th = (float)theta[t] * DEG2RAD;
    const float c = cosf(th), s = sinf(th);
    const float xj = fmaf((float)j, STEP, -1.0f);
    const float s181 = s * 181.0f, c181 = c * 181.0f;
    const float bx = fmaf(c, xj, 1.0f) * 181.0f;
    const float by = fmaf(-s, xj, 1.0f) * 181.0f;
    const float* img0 = x;
    const float* img1 = x + 65536;
    float acc0 = 0.f, acc1 = 0.f;
    for (int i = chunk; i < G; i += 4) {
        const float xi = fmaf((float)i, STEP, -1.0f);
        const float ix = fmaf(s181, xi, bx);
        const float iy = fmaf(c181, xi, by);
        const float fx = floorf(ix), fy = floorf(iy);
        const int ix0 = (int)fx, iy0 = (int)fy;
        const float wx1 = ix - fx, wy1 = iy - fy;
        const float wx0 = 1.f - wx1, wy0 = 1.f - wy1;
        const int cc0 = ix0 - 53, cc1 = cc0 + 1, rr0 = iy0 - 53, rr1 = rr0 + 1;
        const float wxa = ((unsigned)cc0 < 256u) ? wx0 : 0.f;
        const float wxb = ((unsigned)cc1 < 256u) ? wx1 : 0.f;
        const float wya = ((unsigned)rr0 < 256u) ? wy0 : 0.f;
        const float wyb = ((unsigned)rr1 < 256u) ? wy1 : 0.f;
        const int c0c = min(max(cc0, 0), 255), c1c = min(max(cc1, 0), 255);
        const int r0b = min(max(rr0, 0), 255) << 8, r1b = min(max(rr1, 0), 255) << 8;
        const float w00 = wya * wxa, w01 = wya * wxb, w10 = wyb * wxa, w11 = wyb * wxb;
        acc0 = fmaf(img0[r0b + c0c], w00, acc0);
        acc0 = fmaf(img0[r0b + c1c], w01, acc0);
        acc0 = fmaf(img0[r1b + c0c], w10, acc0);
        acc0 = fmaf(img0[r1b + c1c], w11, acc0);
        acc1 = fmaf(img1[r0b + c0c], w00, acc1);
        acc1 = fmaf(img1[r0b + c1c], w01, acc1);
        acc1 = fmaf(img1[r1b + c0c], w10, acc1);
        acc1 = fmaf(img1[r1b + c1c], w11, acc1);
    }
    __shared__ float red[2][4][64];
    red[0][chunk][jl] = acc0;
    red[1][chunk][jl] = acc1;
    __syncthreads();
    if (threadIdx.y < 2 && j < G) {
        const int n = threadIdx.y;
        out[n * (G * NT) + j * NT + t] =
            red[n][0][jl] + red[n][1][jl] + red[n][2][jl] + red[n][3][jl];
    }
}

// ------------- prep: canvases + bbox table + zero(out) ---------------------
__global__ __launch_bounds__(256) void prep_k(
    const float* __restrict__ x, const int* __restrict__ theta,
    f32x2* __restrict__ xIc, f32x2* __restrict__ xTIc,
    int4* __restrict__ bbox, float* __restrict__ out)
{
    const int bid = blockIdx.x;
    const int tx = threadIdx.x, ty = threadIdx.y;
    const int tid = ty * 32 + tx;

    if (bid < 81) {
        __shared__ f32x2 tl[32][33];
        const int cx0 = (bid % 9) * 32, cy0 = (bid / 9) * 32;
        #pragma unroll
        for (int dy = 0; dy < 32; dy += 8) {
            const int cy = cy0 + ty + dy, cx = cx0 + tx;
            const int pr = cy - 3, pc = cx - 3;
            f32x2 v = {0.0f, 0.0f};
            if ((unsigned)pr < 256u && (unsigned)pc < 256u) {
                const int p = pr * 256 + pc;
                v.x = x[p]; v.y = x[p + 65536];
            }
            if (cy < CH && cx < CW) xIc[cy * CW + cx] = v;
            tl[ty + dy][tx] = v;
        }
        __syncthreads();
        #pragma unroll
        for (int dy = 0; dy < 32; dy += 8) {
            const int rp = cx0 + ty + dy, cp = cy0 + tx;
            if (rp < CH && cp < CW) xTIc[rp * CW + cp] = tl[tx][ty + dy];
        }
    } else if (bid < 107) {
        const int tuple = (bid - 81) * 256 + tid;
        if (tuple < NTUPLE) {
            const int tg  = tuple / 72, rem = tuple - tg * 72;
            const int jb  = rem / 12,   ib  = rem - jb * 12;
            const float thA = (float)theta[tg * 2]     * DEG2RAD;
            const float thB = (float)theta[tg * 2 + 1] * DEG2RAD;
            const float cA = cosf(thA), sA = sinf(thA);
            const float cB = cosf(thB), sB = sinf(thB);
            const float xjm = fmaf((float)(jb * 64),      STEP, -1.0f);
            const float xjM = fmaf((float)(jb * 64 + 63), STEP, -1.0f);
            const float xim = fmaf((float)(ib * 32),      STEP, -1.0f);
            const float xiM = fmaf((float)(ib * 32 + 31), STEP, -1.0f);
            float ixmin = 1e30f, ixmax = -1e30f, iymin = 1e30f, iymax = -1e30f;
            #pragma unroll
            for (int qq = 0; qq < 8; ++qq) {
                const float cc  = (qq & 4) ? cB : cA;
                const float ss  = (qq & 4) ? sB : sA;
                const float xjc = (qq & 1) ? xjM : xjm;
                const float xic = (qq & 2) ? xiM : xim;
                const float bxq = fmaf(cc,  xjc, 1.0f) * 181.0f;
                const float byq = fmaf(-ss, xjc, 1.0f) * 181.0f;
                const float ixq = fmaf(ss * 181.0f, xic, bxq);
                const float iyq = fmaf(cc * 181.0f, xic, byq);
                ixmin = fminf(ixmin, ixq); ixmax = fmaxf(ixmax, ixq);
                iymin = fminf(iymin, iyq); iymax = fmaxf(iymax, iyq);
            }
            const int caseA = (fabsf(cA) + fabsf(cB) >= fabsf(sA) + fabsf(sB));
            const float Umin = caseA ? iymin : ixmin;
            const float Umax = caseA ? iymax : ixmax;
            const float Vmin = caseA ? ixmin : iymin;
            const int r0 = (int)floorf(Umin) - 1;
            const int c0 = (int)floorf(Vmin) - 1;
            int rows = (int)floorf(Umax) - (int)floorf(Umin) + 4;
            rows = min(rows, TROWS);
            const int nchunk = (rows * TS2 + 127) >> 7;     // <= 47
            const int r0p = r0 - PADB, c0p = c0 - PADB;
            const int tyLast = (nchunk * 128 - 1) / TS2;
            const int safe = (r0p >= -3) && (r0p + tyLast <= 256)
                          && (c0p >= -3) && (c0p + 79 <= 257);
            bbox[tuple] = make_int4(r0p, c0p,
                                    nchunk | (safe << 8) | (caseA << 9),
                                    -(r0 * TS2 + c0));
        }
    } else {
        const int idx = (bid - 107) * 256 + tid;            // out: 130680 f32
        if (idx < 32670) ((float4*)out)[idx] = make_float4(0.f, 0.f, 0.f, 0.f);
    }
}

// ---------------- staging helpers ------------------------------------------
template<bool SAFE>
__device__ __forceinline__ void stage_direct(f32x2* tile, const f32x2* __restrict__ srcC,
    int r0p, int c0p, int nchunk, int wid, int lane2)
{
    const int B = (r0p + 3) * CW + (c0p + 3);
    for (int h = wid; h < nchunk; h += 8) {
        const int hs   = __builtin_amdgcn_readfirstlane(h);
        const int cell = (hs << 7) + lane2;
        const int tyc  = cell / TS2;
        const int txc  = cell - tyc * TS2;
        int idx;
        if (SAFE) {
            idx = tyc * CW + txc + B;
        } else {
            const int rc = min(max(r0p + tyc, -3), 256) + 3;
            const int cc = min(max(c0p + txc, -3), 257) + 3;
            idx = rc * CW + cc;
        }
        GLOAD16(srcC + idx, (char*)tile + (hs << 10));
    }
}

template<bool SAFE>
__device__ __forceinline__ void loads_reg(f32x4 (&st)[6], const f32x2* __restrict__ srcC,
    int r0p, int c0p, int nchunk, int wid, int lane2)
{
    const int B = (r0p + 3) * CW + (c0p + 3);
    #pragma unroll
    for (int u = 0; u < 6; ++u) {
        const int h = wid + (u << 3);
        if (h < nchunk) {
            const int cell = (h << 7) + lane2;
            const int tyc  = cell / TS2;
            const int txc  = cell - tyc * TS2;
            int idx;
            if (SAFE) {
                idx = tyc * CW + txc + B;
            } else {
                const int rc = min(max(r0p + tyc, -3), 256) + 3;
                const int cc = min(max(c0p + txc, -3), 257) + 3;
                idx = rc * CW + cc;
            }
            const f32x2* gp = srcC + idx;     // 8B-aligned dwordx2 loads
            const f32x2 a = gp[0], b = gp[1];
            st[u].x = a.x; st[u].y = a.y; st[u].z = b.x; st[u].w = b.y;
        }
    }
}

__device__ __forceinline__ void write_reg(f32x2* tile, const f32x4 (&st)[6],
    int nchunk, int wid, int lane)
{
    #pragma unroll
    for (int u = 0; u < 6; ++u) {
        const int h = wid + (u << 3);
        if (h < nchunk)
            *(f32x4*)((char*)tile + (h << 10) + (lane << 4)) = st[u];
    }
}

// ---------------- gather inner loop (8 i-steps) ----------------------------
template<bool TAIL>
__device__ __forceinline__ void gather8(const f32x2* __restrict__ tl,
    float Uf, float Vf, float dU, float dV, int nbase, int iexc,
    f32x2& acc0, f32x2& acc1)
{
    #pragma unroll
    for (int k = 0; k < 8; ++k) {
        const float fU = floorf(Uf), fV = floorf(Vf);
        float wU1 = Uf - fU;
        const float wV1 = Vf - fV;
        float wU0 = 1.0f - wU1;
        const float wV0 = 1.0f - wV1;
        // fU*80+fV exact (integers < 2^24); rel = ty*80+tx in [0, 6080)
        const int rel = (int)fmaf(fU, (float)TS2, fV) + nbase;
        const f32x2 t00 = tl[rel];
        const f32x2 t01 = tl[rel + 1];
        const f32x2 t10 = tl[rel + TS2];
        const f32x2 t11 = tl[rel + TS2 + 1];
        if (TAIL && k >= iexc) { wU0 = 0.0f; wU1 = 0.0f; }   // phantom i >= G
        f32x2 r0v = t00 * (f32x2){wV0, wV0};
        r0v = __builtin_elementwise_fma(t01, (f32x2){wV1, wV1}, r0v);
        f32x2 r1v = t10 * (f32x2){wV0, wV0};
        r1v = __builtin_elementwise_fma(t11, (f32x2){wV1, wV1}, r1v);
        acc0 = __builtin_elementwise_fma(r0v, (f32x2){wU0, wU0}, acc0);
        acc1 = __builtin_elementwise_fma(r1v, (f32x2){wU1, wU1}, acc1);
        Uf += dU; Vf += dV;
    }
}

// ---------------- main tiled gather ----------------------------------------
__global__ __launch_bounds__(512, 6) void radon_tile3(
    const f32x2* __restrict__ xIc, const f32x2* __restrict__ xTIc,
    const int*   __restrict__ theta, const int4* __restrict__ bbox,
    float* __restrict__ out)
{
    __shared__ f32x2 tile[NTILE];          // 49,152 B -> 3 blocks/CU

    const int blk  = blockIdx.x;           // 0..539
    const int z    = blockIdx.y;           // 0..3, handles ib = 3z..3z+2
    const int tg   = blk / 6;
    const int jb   = blk - tg * 6;
    const int tid  = threadIdx.x;
    const int lane = tid & 63;
    const int wid  = tid >> 6;
    const int a    = wid >> 2;             // angle of pair
    const int jh   = (wid >> 1) & 1;       // j half (32)
    const int qq   = wid & 1;              // i 16-group
    const int jl   = lane & 31;
    const int kk   = lane >> 5;            // i 8-subgroup within wave

    const int t = tg * 2 + a;
    const float th = (float)theta[t] * DEG2RAD;
    const float c = cosf(th), s = sinf(th);
    const float s181 = s * 181.0f, c181 = c * 181.0f;

    const int   j  = jb * 64 + jh * 32 + jl;   // phantom j >= 363 ok
    const float xj = fmaf((float)j, STEP, -1.0f);
    const float bx = fmaf(c,  xj, 1.0f) * 181.0f;
    const float by = fmaf(-s, xj, 1.0f) * 181.0f;

    const int lane2 = lane * 2;
    const float fiofs = (float)(qq * 16 + kk * 8);

    // ---- per-pair uniforms (case identical across the 3 subtiles) ----
    const int tb = (tg * 6 + jb) * 12 + z * 3;
    const int4 bbv0 = bbox[tb], bbv1 = bbox[tb + 1], bbv2 = bbox[tb + 2];
    const int fl0 = __builtin_amdgcn_readfirstlane(bbv0.z);
    const int fl1 = __builtin_amdgcn_readfirstlane(bbv1.z);
    const int fl2 = __builtin_amdgcn_readfirstlane(bbv2.z);
    const int r0p0 = __builtin_amdgcn_readfirstlane(bbv0.x);
    const int r0p1 = __builtin_amdgcn_readfirstlane(bbv1.x);
    const int r0p2 = __builtin_amdgcn_readfirstlane(bbv2.x);
    const int c0p0 = __builtin_amdgcn_readfirstlane(bbv0.y);
    const int c0p1 = __builtin_amdgcn_readfirstlane(bbv1.y);
    const int c0p2 = __builtin_amdgcn_readfirstlane(bbv2.y);
    const int nb0 = __builtin_amdgcn_readfirstlane(bbv0.w);
    const int nb1 = __builtin_amdgcn_readfirstlane(bbv1.w);
    const int nb2 = __builtin_amdgcn_readfirstlane(bbv2.w);

    const int caseA = (fl0 >> 9) & 1;
    const f32x2* __restrict__ srcC = caseA ? xIc : xTIc;

    const float slopeU = caseA ? c181 : s181;
    const float slopeV = caseA ? s181 : c181;
    const float dU = slopeU * STEP;
    const float dV = slopeV * STEP;
    const float U00 = (caseA ? by : bx) - slopeU;
    const float V00 = (caseA ? bx : by) - slopeV;

    f32x2 acc0 = {0.0f, 0.0f}, acc1 = {0.0f, 0.0f};
    f32x4 st[6];
    const int ib0 = z * 3;

    // ---- gather for one subtile (macro-ish lambda) ----
    auto do_gather = [&](int ib, int nbase) {
        const int i0 = ib * 32;
        const float fi = (float)i0 + fiofs;
        const float Uf = fmaf(dU, fi, U00);
        const float Vf = fmaf(dV, fi, V00);
        const int ibase = i0 + qq * 16 + kk * 8;
        if (i0 + qq * 16 + 15 < G) {
            gather8<false>(tile, Uf, Vf, dU, dV, nbase, 8, acc0, acc1);
        } else {
            gather8<true>(tile, Uf, Vf, dU, dV, nbase, G - ibase, acc0, acc1);
        }
    };

    // ---- prologue: stage subtile 0 directly ----
    if (fl0 & 256) stage_direct<true >(tile, srcC, r0p0, c0p0, fl0 & 255, wid, lane2);
    else           stage_direct<false>(tile, srcC, r0p0, c0p0, fl0 & 255, wid, lane2);
    __syncthreads();                       // drains vmcnt -> tile 0 ready

    // ---- iter 0: prefetch 1, gather 0 ----
    if (fl1 & 256) loads_reg<true >(st, srcC, r0p1, c0p1, fl1 & 255, wid, lane2);
    else           loads_reg<false>(st, srcC, r0p1, c0p1, fl1 & 255, wid, lane2);
    do_gather(ib0, nb0);
    __syncthreads();
    write_reg(tile, st, fl1 & 255, wid, lane);
    __syncthreads();

    // ---- iter 1: prefetch 2, gather 1 ----
    if (fl2 & 256) loads_reg<true >(st, srcC, r0p2, c0p2, fl2 & 255, wid, lane2);
    else           loads_reg<false>(st, srcC, r0p2, c0p2, fl2 & 255, wid, lane2);
    do_gather(ib0 + 1, nb1);
    __syncthreads();
    write_reg(tile, st, fl2 & 255, wid, lane);
    __syncthreads();

    // ---- iter 2: gather 2 ----
    do_gather(ib0 + 2, nb2);

    // ---- reduce (qq waves x kk lanes) and atomically add into out ----
    __syncthreads();
    f32x2* red = tile;
    red[wid * 64 + lane] = acc0 + acc1;
    __syncthreads();

    if (tid < 128) {
        const int aa = tid >> 6, jj = tid & 63;
        const int jhh = jj >> 5, jll = jj & 31;
        const int w0 = aa * 4 + jhh * 2;
        f32x2 v = red[w0 * 64 + jll];
        v += red[w0 * 64 + jll + 32];
        v += red[(w0 + 1) * 64 + jll];
        v += red[(w0 + 1) * 64 + jll + 32];
        const int jo = jb * 64 + jj;
        if (jo < G) {
            const int tt = tg * 2 + aa;
            atomicAdd(&out[jo * NT + tt],          v.x);   // n = 0
            atomicAdd(&out[G * NT + jo * NT + tt], v.y);   // n = 1
        }
    }
}

extern "C" void kernel_launch(void* const* d_in, const int* in_sizes, int n_in,
                              void* d_out, int out_size, void* d_ws, size_t ws_size,
                              hipStream_t stream) {
    const float* x     = (const float*)d_in[0];
    const int*   theta = (const int*)d_in[1];
    float*       out   = (float*)d_out;

    const size_t XIC_OFF  = 0;
    const size_t XTIC_OFF = (size_t)CH * CW * 8;                 // 544,960
    const size_t BBOX_OFF = 2 * XTIC_OFF;                        // 1,089,920
    const size_t NEED     = BBOX_OFF + (size_t)NTUPLE * 16;      // ~1.19 MiB

    if (ws_size < NEED) {   // fallback: known-good gather kernel
        hipLaunchKernelGGL(radon_fwd, dim3(NT * NJB), dim3(64, 4), 0, stream,
                           x, theta, out);
        return;
    }

    f32x2* xIc  = (f32x2*)((char*)d_ws + XIC_OFF);
    f32x2* xTIc = (f32x2*)((char*)d_ws + XTIC_OFF);
    int4*  bbox = (int4*)((char*)d_ws + BBOX_OFF);

    hipLaunchKernelGGL(prep_k, dim3(235), dim3(32, 8), 0, stream,
                       x, theta, xIc, xTIc, bbox, out);
    hipLaunchKernelGGL(radon_tile3, dim3(540, 4), dim3(512), 0, stream,
                       xIc, xTIc, theta, bbox, out);
}

// Round 3
// 45.090 us; speedup vs baseline: 1.2957x; 1.2957x over previous
//
#include <hip/hip_runtime.h>
#include <math.h>

// Radon forward, exact reference semantics (rotated-lattice bilinear gather).
//
// Round-9 changes vs round 8 (58.4 us total; tile3 54-56 us -- REGRESSION):
//  * Post-mortem r8: bank conflicts DID drop 8.80M -> 3.02M (TS2=80 theory
//    confirmed), but register-staging spilled: VGPR_Count stayed 40 under
//    __launch_bounds__(512,6), so st[6] lived in SCRATCH -> 76 MB HBM
//    writes + 13 MB reads of pure spill traffic (rule-#20 trap).
//  * Revert staging to round-7 global_load_lds direct path (no VGPR
//    round-trip, no scratch), for ALL subtiles. KEEP TS2=80 (bank fix).
//  * Keep hoisted per-pair uniforms (case/slopes/dU/dV computed once).
//  * Geometry: V-span <= ~71 < 80 cols, U-span rows <= ~72 < 76,
//    nchunk <= 45 <= 48. LDS 49,152 B -> 3 blocks/CU.

#define G       363
#define NT      180
#define PADB    53
#define STEP    (2.0f / 362.0f)
#define DEG2RAD 0.017453292519943295f

#define TS2     80          // tile row length (f32x2 cells), MULTIPLE OF 16
#define TROWS   76          // max tile rows
#define NCHK    48          // max staging chunks (128 cells each)
#define NTILE   (NCHK * 128)   // 6144 cells = 49,152 B -> 3 blocks/CU
#define NJB     6
#define CW      262         // canvas cols
#define CH      260         // canvas rows  (image interior at [3..258]x[3..258])
#define NTUPLE  (90 * 6 * 12)

typedef __attribute__((ext_vector_type(2))) float f32x2;

#define GLOAD16(gp, lp) __builtin_amdgcn_global_load_lds(                     \
    (const __attribute__((address_space(1))) void*)(gp),                      \
    (__attribute__((address_space(3))) void*)(lp), 16, 0, 0)

// ---------------- fallback gather kernel (known-good, round 1) -------------
__global__ __launch_bounds__(256) void radon_fwd(
    const float* __restrict__ x, const int* __restrict__ theta,
    float* __restrict__ out)
{
    const int t = blockIdx.x / NJB, jb = blockIdx.x % NJB;
    const int jl = threadIdx.x, chunk = threadIdx.y;
    const int j = jb * 64 + jl;
    const float th = (float)theta[t] * DEG2RAD;
    const float c = cosf(th), s = sinf(th);
    const float xj = fmaf((float)j, STEP, -1.0f);
    const float s181 = s * 181.0f, c181 = c * 181.0f;
    const float bx = fmaf(c, xj, 1.0f) * 181.0f;
    const float by = fmaf(-s, xj, 1.0f) * 181.0f;
    const float* img0 = x;
    const float* img1 = x + 65536;
    float acc0 = 0.f, acc1 = 0.f;
    for (int i = chunk; i < G; i += 4) {
        const float xi = fmaf((float)i, STEP, -1.0f);
        const float ix = fmaf(s181, xi, bx);
        const float iy = fmaf(c181, xi, by);
        const float fx = floorf(ix), fy = floorf(iy);
        const int ix0 = (int)fx, iy0 = (int)fy;
        const float wx1 = ix - fx, wy1 = iy - fy;
        const float wx0 = 1.f - wx1, wy0 = 1.f - wy1;
        const int cc0 = ix0 - 53, cc1 = cc0 + 1, rr0 = iy0 - 53, rr1 = rr0 + 1;
        const float wxa = ((unsigned)cc0 < 256u) ? wx0 : 0.f;
        const float wxb = ((unsigned)cc1 < 256u) ? wx1 : 0.f;
        const float wya = ((unsigned)rr0 < 256u) ? wy0 : 0.f;
        const float wyb = ((unsigned)rr1 < 256u) ? wy1 : 0.f;
        const int c0c = min(max(cc0, 0), 255), c1c = min(max(cc1, 0), 255);
        const int r0b = min(max(rr0, 0), 255) << 8, r1b = min(max(rr1, 0), 255) << 8;
        const float w00 = wya * wxa, w01 = wya * wxb, w10 = wyb * wxa, w11 = wyb * wxb;
        acc0 = fmaf(img0[r0b + c0c], w00, acc0);
        acc0 = fmaf(img0[r0b + c1c], w01, acc0);
        acc0 = fmaf(img0[r1b + c0c], w10, acc0);
        acc0 = fmaf(img0[r1b + c1c], w11, acc0);
        acc1 = fmaf(img1[r0b + c0c], w00, acc1);
        acc1 = fmaf(img1[r0b + c1c], w01, acc1);
        acc1 = fmaf(img1[r1b + c0c], w10, acc1);
        acc1 = fmaf(img1[r1b + c1c], w11, acc1);
    }
    __shared__ float red[2][4][64];
    red[0][chunk][jl] = acc0;
    red[1][chunk][jl] = acc1;
    __syncthreads();
    if (threadIdx.y < 2 && j < G) {
        const int n = threadIdx.y;
        out[n * (G * NT) + j * NT + t] =
            red[n][0][jl] + red[n][1][jl] + red[n][2][jl] + red[n][3][jl];
    }
}

// ------------- prep: canvases + bbox table + zero(out) ---------------------
__global__ __launch_bounds__(256) void prep_k(
    const float* __restrict__ x, const int* __restrict__ theta,
    f32x2* __restrict__ xIc, f32x2* __restrict__ xTIc,
    int4* __restrict__ bbox, float* __restrict__ out)
{
    const int bid = blockIdx.x;
    const int tx = threadIdx.x, ty = threadIdx.y;
    const int tid = ty * 32 + tx;

    if (bid < 81) {
        __shared__ f32x2 tl[32][33];
        const int cx0 = (bid % 9) * 32, cy0 = (bid / 9) * 32;
        #pragma unroll
        for (int dy = 0; dy < 32; dy += 8) {
            const int cy = cy0 + ty + dy, cx = cx0 + tx;
            const int pr = cy - 3, pc = cx - 3;
            f32x2 v = {0.0f, 0.0f};
            if ((unsigned)pr < 256u && (unsigned)pc < 256u) {
                const int p = pr * 256 + pc;
                v.x = x[p]; v.y = x[p + 65536];
            }
            if (cy < CH && cx < CW) xIc[cy * CW + cx] = v;
            tl[ty + dy][tx] = v;
        }
        __syncthreads();
        #pragma unroll
        for (int dy = 0; dy < 32; dy += 8) {
            const int rp = cx0 + ty + dy, cp = cy0 + tx;
            if (rp < CH && cp < CW) xTIc[rp * CW + cp] = tl[tx][ty + dy];
        }
    } else if (bid < 107) {
        const int tuple = (bid - 81) * 256 + tid;
        if (tuple < NTUPLE) {
            const int tg  = tuple / 72, rem = tuple - tg * 72;
            const int jb  = rem / 12,   ib  = rem - jb * 12;
            const float thA = (float)theta[tg * 2]     * DEG2RAD;
            const float thB = (float)theta[tg * 2 + 1] * DEG2RAD;
            const float cA = cosf(thA), sA = sinf(thA);
            const float cB = cosf(thB), sB = sinf(thB);
            const float xjm = fmaf((float)(jb * 64),      STEP, -1.0f);
            const float xjM = fmaf((float)(jb * 64 + 63), STEP, -1.0f);
            const float xim = fmaf((float)(ib * 32),      STEP, -1.0f);
            const float xiM = fmaf((float)(ib * 32 + 31), STEP, -1.0f);
            float ixmin = 1e30f, ixmax = -1e30f, iymin = 1e30f, iymax = -1e30f;
            #pragma unroll
            for (int qq = 0; qq < 8; ++qq) {
                const float cc  = (qq & 4) ? cB : cA;
                const float ss  = (qq & 4) ? sB : sA;
                const float xjc = (qq & 1) ? xjM : xjm;
                const float xic = (qq & 2) ? xiM : xim;
                const float bxq = fmaf(cc,  xjc, 1.0f) * 181.0f;
                const float byq = fmaf(-ss, xjc, 1.0f) * 181.0f;
                const float ixq = fmaf(ss * 181.0f, xic, bxq);
                const float iyq = fmaf(cc * 181.0f, xic, byq);
                ixmin = fminf(ixmin, ixq); ixmax = fmaxf(ixmax, ixq);
                iymin = fminf(iymin, iyq); iymax = fmaxf(iymax, iyq);
            }
            const int caseA = (fabsf(cA) + fabsf(cB) >= fabsf(sA) + fabsf(sB));
            const float Umin = caseA ? iymin : ixmin;
            const float Umax = caseA ? iymax : ixmax;
            const float Vmin = caseA ? ixmin : iymin;
            const int r0 = (int)floorf(Umin) - 1;
            const int c0 = (int)floorf(Vmin) - 1;
            int rows = (int)floorf(Umax) - (int)floorf(Umin) + 4;
            rows = min(rows, TROWS);
            const int nchunk = (rows * TS2 + 127) >> 7;     // <= 45
            const int r0p = r0 - PADB, c0p = c0 - PADB;
            const int tyLast = (nchunk * 128 - 1) / TS2;
            const int safe = (r0p >= -3) && (r0p + tyLast <= 256)
                          && (c0p >= -3) && (c0p + 79 <= 257);
            bbox[tuple] = make_int4(r0p, c0p,
                                    nchunk | (safe << 8) | (caseA << 9),
                                    -(r0 * TS2 + c0));
        }
    } else {
        const int idx = (bid - 107) * 256 + tid;            // out: 130680 f32
        if (idx < 32670) ((float4*)out)[idx] = make_float4(0.f, 0.f, 0.f, 0.f);
    }
}

// ---------------- staging: 16B/lane global_load_lds, linear LDS dest -------
template<bool SAFE>
__device__ __forceinline__ void stage_direct(f32x2* tile, const f32x2* __restrict__ srcC,
    int r0p, int c0p, int nchunk, int wid, int lane2)
{
    const int B = (r0p + 3) * CW + (c0p + 3);
    for (int h = wid; h < nchunk; h += 8) {
        const int hs   = __builtin_amdgcn_readfirstlane(h);
        const int cell = (hs << 7) + lane2;
        const int tyc  = cell / TS2;
        const int txc  = cell - tyc * TS2;
        int idx;
        if (SAFE) {
            idx = tyc * CW + txc + B;
        } else {
            const int rc = min(max(r0p + tyc, -3), 256) + 3;
            const int cc = min(max(c0p + txc, -3), 257) + 3;
            idx = rc * CW + cc;
        }
        GLOAD16(srcC + idx, (char*)tile + (hs << 10));
    }
}

// ---------------- gather inner loop (8 i-steps) ----------------------------
template<bool TAIL>
__device__ __forceinline__ void gather8(const f32x2* __restrict__ tl,
    float Uf, float Vf, float dU, float dV, int nbase, int iexc,
    f32x2& acc0, f32x2& acc1)
{
    #pragma unroll
    for (int k = 0; k < 8; ++k) {
        const float fU = floorf(Uf), fV = floorf(Vf);
        float wU1 = Uf - fU;
        const float wV1 = Vf - fV;
        float wU0 = 1.0f - wU1;
        const float wV0 = 1.0f - wV1;
        // fU*80+fV exact (integers < 2^24); rel = ty*80+tx in [0, 6080)
        const int rel = (int)fmaf(fU, (float)TS2, fV) + nbase;
        const f32x2 t00 = tl[rel];
        const f32x2 t01 = tl[rel + 1];
        const f32x2 t10 = tl[rel + TS2];
        const f32x2 t11 = tl[rel + TS2 + 1];
        if (TAIL && k >= iexc) { wU0 = 0.0f; wU1 = 0.0f; }   // phantom i >= G
        f32x2 r0v = t00 * (f32x2){wV0, wV0};
        r0v = __builtin_elementwise_fma(t01, (f32x2){wV1, wV1}, r0v);
        f32x2 r1v = t10 * (f32x2){wV0, wV0};
        r1v = __builtin_elementwise_fma(t11, (f32x2){wV1, wV1}, r1v);
        acc0 = __builtin_elementwise_fma(r0v, (f32x2){wU0, wU0}, acc0);
        acc1 = __builtin_elementwise_fma(r1v, (f32x2){wU1, wU1}, acc1);
        Uf += dU; Vf += dV;
    }
}

// ---------------- main tiled gather ----------------------------------------
__global__ __launch_bounds__(512) void radon_tile3(
    const f32x2* __restrict__ xIc, const f32x2* __restrict__ xTIc,
    const int*   __restrict__ theta, const int4* __restrict__ bbox,
    float* __restrict__ out)
{
    __shared__ f32x2 tile[NTILE];          // 49,152 B -> 3 blocks/CU

    const int blk  = blockIdx.x;           // 0..539
    const int z    = blockIdx.y;           // 0..3, handles ib = 3z..3z+2
    const int tg   = blk / 6;
    const int jb   = blk - tg * 6;
    const int tid  = threadIdx.x;
    const int lane = tid & 63;
    const int wid  = tid >> 6;
    const int a    = wid >> 2;             // angle of pair
    const int jh   = (wid >> 1) & 1;       // j half (32)
    const int qq   = wid & 1;              // i 16-group
    const int jl   = lane & 31;
    const int kk   = lane >> 5;            // i 8-subgroup within wave

    const int t = tg * 2 + a;
    const float th = (float)theta[t] * DEG2RAD;
    const float c = cosf(th), s = sinf(th);
    const float s181 = s * 181.0f, c181 = c * 181.0f;

    const int   j  = jb * 64 + jh * 32 + jl;   // phantom j >= 363 ok
    const float xj = fmaf((float)j, STEP, -1.0f);
    const float bx = fmaf(c,  xj, 1.0f) * 181.0f;
    const float by = fmaf(-s, xj, 1.0f) * 181.0f;

    const int lane2 = lane * 2;
    const float fiofs = (float)(qq * 16 + kk * 8);

    // ---- per-pair uniforms (case identical across the 3 subtiles) ----
    const int tb = (tg * 6 + jb) * 12 + z * 3;
    const int caseA = (__builtin_amdgcn_readfirstlane(bbox[tb].z) >> 9) & 1;
    const f32x2* __restrict__ srcC = caseA ? xIc : xTIc;

    const float slopeU = caseA ? c181 : s181;
    const float slopeV = caseA ? s181 : c181;
    const float dU = slopeU * STEP;
    const float dV = slopeV * STEP;
    const float U00 = (caseA ? by : bx) - slopeU;
    const float V00 = (caseA ? bx : by) - slopeV;

    f32x2 acc0 = {0.0f, 0.0f}, acc1 = {0.0f, 0.0f};
    const int ib0 = z * 3;

    for (int ibi = 0; ibi < 3; ++ibi) {
        const int ib = ib0 + ibi;
        const int4 bb = bbox[tb + ibi];
        const int r0p    = __builtin_amdgcn_readfirstlane(bb.x);
        const int c0p    = __builtin_amdgcn_readfirstlane(bb.y);
        const int flags  = __builtin_amdgcn_readfirstlane(bb.z);
        const int nbase  = __builtin_amdgcn_readfirstlane(bb.w);
        const int nchunk = flags & 255;
        const int safe   = (flags >> 8) & 1;

        __syncthreads();                   // previous tile fully consumed

        if (safe) stage_direct<true >(tile, srcC, r0p, c0p, nchunk, wid, lane2);
        else      stage_direct<false>(tile, srcC, r0p, c0p, nchunk, wid, lane2);
        __syncthreads();                   // drains vmcnt -> tile ready

        // ---- gather: 8 samples/lane, incremental U/V walk ----
        const int i0 = ib * 32;
        const float fi = (float)i0 + fiofs;
        const float Uf = fmaf(dU, fi, U00);
        const float Vf = fmaf(dV, fi, V00);
        const int ibase = i0 + qq * 16 + kk * 8;

        if (i0 + qq * 16 + 15 < G) {       // wave-uniform (qq per-wave)
            gather8<false>(tile, Uf, Vf, dU, dV, nbase, 8, acc0, acc1);
        } else {
            gather8<true>(tile, Uf, Vf, dU, dV, nbase, G - ibase, acc0, acc1);
        }
    }

    // ---- reduce (qq waves x kk lanes) and atomically add into out ----
    __syncthreads();
    f32x2* red = tile;
    red[wid * 64 + lane] = acc0 + acc1;
    __syncthreads();

    if (tid < 128) {
        const int aa = tid >> 6, jj = tid & 63;
        const int jhh = jj >> 5, jll = jj & 31;
        const int w0 = aa * 4 + jhh * 2;
        f32x2 v = red[w0 * 64 + jll];
        v += red[w0 * 64 + jll + 32];
        v += red[(w0 + 1) * 64 + jll];
        v += red[(w0 + 1) * 64 + jll + 32];
        const int jo = jb * 64 + jj;
        if (jo < G) {
            const int tt = tg * 2 + aa;
            atomicAdd(&out[jo * NT + tt],          v.x);   // n = 0
            atomicAdd(&out[G * NT + jo * NT + tt], v.y);   // n = 1
        }
    }
}

extern "C" void kernel_launch(void* const* d_in, const int* in_sizes, int n_in,
                              void* d_out, int out_size, void* d_ws, size_t ws_size,
                              hipStream_t stream) {
    const float* x     = (const float*)d_in[0];
    const int*   theta = (const int*)d_in[1];
    float*       out   = (float*)d_out;

    const size_t XIC_OFF  = 0;
    const size_t XTIC_OFF = (size_t)CH * CW * 8;                 // 544,960
    const size_t BBOX_OFF = 2 * XTIC_OFF;                        // 1,089,920
    const size_t NEED     = BBOX_OFF + (size_t)NTUPLE * 16;      // ~1.19 MiB

    if (ws_size < NEED) {   // fallback: known-good gather kernel
        hipLaunchKernelGGL(radon_fwd, dim3(NT * NJB), dim3(64, 4), 0, stream,
                           x, theta, out);
        return;
    }

    f32x2* xIc  = (f32x2*)((char*)d_ws + XIC_OFF);
    f32x2* xTIc = (f32x2*)((char*)d_ws + XTIC_OFF);
    int4*  bbox = (int4*)((char*)d_ws + BBOX_OFF);

    hipLaunchKernelGGL(prep_k, dim3(235), dim3(32, 8), 0, stream,
                       x, theta, xIc, xTIc, bbox, out);
    hipLaunchKernelGGL(radon_tile3, dim3(540, 4), dim3(512), 0, stream,
                       xIc, xTIc, theta, bbox, out);
}

// Round 4
// 44.562 us; speedup vs baseline: 1.3111x; 1.0119x over previous
//
#include <hip/hip_runtime.h>
#include <math.h>

// Radon forward, exact reference semantics (rotated-lattice bilinear gather).
//
// Round-10 changes vs round 9 (45.1 us total; tile3 ~39 us, Occupancy ~42%):
//  * Diagnosis: no pipe saturated; LDS-limited residency (49,152 B -> only
//    3 blocks/CU = 24 waves) leaves the stage->drain->gather latency exposed.
//  * Re-tile: 32j x 24i subtiles, 256-thread blocks (2 angles x 2 j-halves
//    x 16 j-lanes x 4 i-groups of 6). Worst-case spans (caseA |s|<=0.72):
//    rows <= 32|s|+24|c|+4 <= 44, cols <= 32|c|+24|s|+4 <= 44 -> TS2=48
//    (multiple of 16: bank fix preserved), TROWS=44, NCHK=17 -> LDS
//    17,408 B -> 8 blocks/CU x 4 waves = 32 waves = 100% occupancy.
//  * Grid 1080 x 4 (z handles 4 of 16 i-subtiles); same total staging
//    bytes and sample count as round 9.
//  * Epilogue: pure __shfl_xor(16/32) reduce over i-groups, atomicAdd into
//    zeroed out -- no LDS round-trip, no tail barriers.

#define G       363
#define NT      180
#define PADB    53
#define STEP    (2.0f / 362.0f)
#define DEG2RAD 0.017453292519943295f

#define TS2     48          // tile row length (f32x2 cells), MULTIPLE OF 16
#define TROWS   44          // max tile rows
#define NCHK    17          // max staging chunks (128 cells each)
#define NTILE   (NCHK * 128)   // 2176 cells = 17,408 B -> 8 blocks/CU
#define NJB     12          // j-blocks of 32
#define NIB     16          // i-subtiles of 24
#define NJBF    6           // fallback j-blocks of 64
#define CW      262         // canvas cols
#define CH      260         // canvas rows  (image interior at [3..258]x[3..258])
#define NTUPLE  (90 * NJB * NIB)   // 17280

typedef __attribute__((ext_vector_type(2))) float f32x2;

#define GLOAD16(gp, lp) __builtin_amdgcn_global_load_lds(                     \
    (const __attribute__((address_space(1))) void*)(gp),                      \
    (__attribute__((address_space(3))) void*)(lp), 16, 0, 0)

// ---------------- fallback gather kernel (known-good, round 1) -------------
__global__ __launch_bounds__(256) void radon_fwd(
    const float* __restrict__ x, const int* __restrict__ theta,
    float* __restrict__ out)
{
    const int t = blockIdx.x / NJBF, jb = blockIdx.x % NJBF;
    const int jl = threadIdx.x, chunk = threadIdx.y;
    const int j = jb * 64 + jl;
    const float th = (float)theta[t] * DEG2RAD;
    const float c = cosf(th), s = sinf(th);
    const float xj = fmaf((float)j, STEP, -1.0f);
    const float s181 = s * 181.0f, c181 = c * 181.0f;
    const float bx = fmaf(c, xj, 1.0f) * 181.0f;
    const float by = fmaf(-s, xj, 1.0f) * 181.0f;
    const float* img0 = x;
    const float* img1 = x + 65536;
    float acc0 = 0.f, acc1 = 0.f;
    for (int i = chunk; i < G; i += 4) {
        const float xi = fmaf((float)i, STEP, -1.0f);
        const float ix = fmaf(s181, xi, bx);
        const float iy = fmaf(c181, xi, by);
        const float fx = floorf(ix), fy = floorf(iy);
        const int ix0 = (int)fx, iy0 = (int)fy;
        const float wx1 = ix - fx, wy1 = iy - fy;
        const float wx0 = 1.f - wx1, wy0 = 1.f - wy1;
        const int cc0 = ix0 - 53, cc1 = cc0 + 1, rr0 = iy0 - 53, rr1 = rr0 + 1;
        const float wxa = ((unsigned)cc0 < 256u) ? wx0 : 0.f;
        const float wxb = ((unsigned)cc1 < 256u) ? wx1 : 0.f;
        const float wya = ((unsigned)rr0 < 256u) ? wy0 : 0.f;
        const float wyb = ((unsigned)rr1 < 256u) ? wy1 : 0.f;
        const int c0c = min(max(cc0, 0), 255), c1c = min(max(cc1, 0), 255);
        const int r0b = min(max(rr0, 0), 255) << 8, r1b = min(max(rr1, 0), 255) << 8;
        const float w00 = wya * wxa, w01 = wya * wxb, w10 = wyb * wxa, w11 = wyb * wxb;
        acc0 = fmaf(img0[r0b + c0c], w00, acc0);
        acc0 = fmaf(img0[r0b + c1c], w01, acc0);
        acc0 = fmaf(img0[r1b + c0c], w10, acc0);
        acc0 = fmaf(img0[r1b + c1c], w11, acc0);
        acc1 = fmaf(img1[r0b + c0c], w00, acc1);
        acc1 = fmaf(img1[r0b + c1c], w01, acc1);
        acc1 = fmaf(img1[r1b + c0c], w10, acc1);
        acc1 = fmaf(img1[r1b + c1c], w11, acc1);
    }
    __shared__ float red[2][4][64];
    red[0][chunk][jl] = acc0;
    red[1][chunk][jl] = acc1;
    __syncthreads();
    if (threadIdx.y < 2 && j < G) {
        const int n = threadIdx.y;
        out[n * (G * NT) + j * NT + t] =
            red[n][0][jl] + red[n][1][jl] + red[n][2][jl] + red[n][3][jl];
    }
}

// ------------- prep: canvases + bbox table + zero(out) ---------------------
// Block roles by blockIdx.x:
//   [0,81)    : interleave image into guarded canvases (normal + transposed)
//   [81,149)  : bbox table, one tuple (tg,jb,ib) per thread (17280 tuples)
//   [149,277) : zero out (32670 float4)
__global__ __launch_bounds__(256) void prep_k(
    const float* __restrict__ x, const int* __restrict__ theta,
    f32x2* __restrict__ xIc, f32x2* __restrict__ xTIc,
    int4* __restrict__ bbox, float* __restrict__ out)
{
    const int bid = blockIdx.x;
    const int tx = threadIdx.x, ty = threadIdx.y;
    const int tid = ty * 32 + tx;

    if (bid < 81) {
        __shared__ f32x2 tl[32][33];
        const int cx0 = (bid % 9) * 32, cy0 = (bid / 9) * 32;
        #pragma unroll
        for (int dy = 0; dy < 32; dy += 8) {
            const int cy = cy0 + ty + dy, cx = cx0 + tx;
            const int pr = cy - 3, pc = cx - 3;
            f32x2 v = {0.0f, 0.0f};
            if ((unsigned)pr < 256u && (unsigned)pc < 256u) {
                const int p = pr * 256 + pc;
                v.x = x[p]; v.y = x[p + 65536];
            }
            if (cy < CH && cx < CW) xIc[cy * CW + cx] = v;
            tl[ty + dy][tx] = v;
        }
        __syncthreads();
        #pragma unroll
        for (int dy = 0; dy < 32; dy += 8) {
            const int rp = cx0 + ty + dy, cp = cy0 + tx;
            if (rp < CH && cp < CW) xTIc[rp * CW + cp] = tl[tx][ty + dy];
        }
    } else if (bid < 149) {
        const int tuple = (bid - 81) * 256 + tid;
        if (tuple < NTUPLE) {
            const int tg  = tuple / (NJB * NIB), rem = tuple - tg * (NJB * NIB);
            const int jb  = rem / NIB,   ib  = rem - jb * NIB;
            const float thA = (float)theta[tg * 2]     * DEG2RAD;
            const float thB = (float)theta[tg * 2 + 1] * DEG2RAD;
            const float cA = cosf(thA), sA = sinf(thA);
            const float cB = cosf(thB), sB = sinf(thB);
            const float xjm = fmaf((float)(jb * 32),      STEP, -1.0f);
            const float xjM = fmaf((float)(jb * 32 + 31), STEP, -1.0f);
            const float xim = fmaf((float)(ib * 24),      STEP, -1.0f);
            const float xiM = fmaf((float)(ib * 24 + 23), STEP, -1.0f);
            float ixmin = 1e30f, ixmax = -1e30f, iymin = 1e30f, iymax = -1e30f;
            #pragma unroll
            for (int qq = 0; qq < 8; ++qq) {
                const float cc  = (qq & 4) ? cB : cA;
                const float ss  = (qq & 4) ? sB : sA;
                const float xjc = (qq & 1) ? xjM : xjm;
                const float xic = (qq & 2) ? xiM : xim;
                const float bxq = fmaf(cc,  xjc, 1.0f) * 181.0f;
                const float byq = fmaf(-ss, xjc, 1.0f) * 181.0f;
                const float ixq = fmaf(ss * 181.0f, xic, bxq);
                const float iyq = fmaf(cc * 181.0f, xic, byq);
                ixmin = fminf(ixmin, ixq); ixmax = fmaxf(ixmax, ixq);
                iymin = fminf(iymin, iyq); iymax = fmaxf(iymax, iyq);
            }
            const int caseA = (fabsf(cA) + fabsf(cB) >= fabsf(sA) + fabsf(sB));
            const float Umin = caseA ? iymin : ixmin;
            const float Umax = caseA ? iymax : ixmax;
            const float Vmin = caseA ? ixmin : iymin;
            const int r0 = (int)floorf(Umin) - 1;
            const int c0 = (int)floorf(Vmin) - 1;
            int rows = (int)floorf(Umax) - (int)floorf(Umin) + 4;
            rows = min(rows, TROWS);
            const int nchunk = (rows * TS2 + 127) >> 7;     // <= 17
            const int r0p = r0 - PADB, c0p = c0 - PADB;
            const int tyLast = (nchunk * 128 - 1) / TS2;
            const int safe = (r0p >= -3) && (r0p + tyLast <= 256)
                          && (c0p >= -3) && (c0p + (TS2 - 1) <= 257);
            bbox[tuple] = make_int4(r0p, c0p,
                                    nchunk | (safe << 8) | (caseA << 9),
                                    -(r0 * TS2 + c0));
        }
    } else {
        const int idx = (bid - 149) * 256 + tid;            // out: 130680 f32
        if (idx < 32670) ((float4*)out)[idx] = make_float4(0.f, 0.f, 0.f, 0.f);
    }
}

// ---------------- staging: 16B/lane global_load_lds, linear LDS dest -------
template<bool SAFE>
__device__ __forceinline__ void stage_direct(f32x2* tile, const f32x2* __restrict__ srcC,
    int r0p, int c0p, int nchunk, int wid, int lane2)
{
    const int B = (r0p + 3) * CW + (c0p + 3);
    for (int h = wid; h < nchunk; h += 4) {
        const int hs   = __builtin_amdgcn_readfirstlane(h);
        const int cell = (hs << 7) + lane2;
        const int tyc  = cell / TS2;
        const int txc  = cell - tyc * TS2;
        int idx;
        if (SAFE) {
            idx = tyc * CW + txc + B;
        } else {
            const int rc = min(max(r0p + tyc, -3), 256) + 3;
            const int cc = min(max(c0p + txc, -3), 257) + 3;
            idx = rc * CW + cc;
        }
        GLOAD16(srcC + idx, (char*)tile + (hs << 10));
    }
}

// ---------------- gather inner loop (6 i-steps) ----------------------------
template<bool TAIL>
__device__ __forceinline__ void gather6(const f32x2* __restrict__ tl,
    float Uf, float Vf, float dU, float dV, int nbase, int iexc,
    f32x2& acc0, f32x2& acc1)
{
    #pragma unroll
    for (int k = 0; k < 6; ++k) {
        const float fU = floorf(Uf), fV = floorf(Vf);
        float wU1 = Uf - fU;
        const float wV1 = Vf - fV;
        float wU0 = 1.0f - wU1;
        const float wV0 = 1.0f - wV1;
        // fU*48+fV exact (integers < 2^24); rel = ty*48+tx in [0, 2112)
        const int rel = (int)fmaf(fU, (float)TS2, fV) + nbase;
        const f32x2 t00 = tl[rel];
        const f32x2 t01 = tl[rel + 1];
        const f32x2 t10 = tl[rel + TS2];
        const f32x2 t11 = tl[rel + TS2 + 1];
        if (TAIL && k >= iexc) { wU0 = 0.0f; wU1 = 0.0f; }   // phantom i >= G
        f32x2 r0v = t00 * (f32x2){wV0, wV0};
        r0v = __builtin_elementwise_fma(t01, (f32x2){wV1, wV1}, r0v);
        f32x2 r1v = t10 * (f32x2){wV0, wV0};
        r1v = __builtin_elementwise_fma(t11, (f32x2){wV1, wV1}, r1v);
        acc0 = __builtin_elementwise_fma(r0v, (f32x2){wU0, wU0}, acc0);
        acc1 = __builtin_elementwise_fma(r1v, (f32x2){wU1, wU1}, acc1);
        Uf += dU; Vf += dV;
    }
}

// ---------------- main tiled gather ----------------------------------------
__global__ __launch_bounds__(256) void radon_tile4(
    const f32x2* __restrict__ xIc, const f32x2* __restrict__ xTIc,
    const int*   __restrict__ theta, const int4* __restrict__ bbox,
    float* __restrict__ out)
{
    __shared__ f32x2 tile[NTILE];          // 17,408 B -> 8 blocks/CU

    const int blk  = blockIdx.x;           // 0..1079
    const int z    = blockIdx.y;           // 0..3, handles ib = 4z..4z+3
    const int tg   = blk / NJB;
    const int jb   = blk - tg * NJB;
    const int tid  = threadIdx.x;
    const int lane = tid & 63;
    const int wid  = tid >> 6;             // 0..3
    const int a    = wid >> 1;             // angle of pair
    const int wj   = wid & 1;              // j half (16)
    const int jl   = lane & 15;            // j lane
    const int kk   = lane >> 4;            // i 6-group (0..3)

    const int t = tg * 2 + a;
    const float th = (float)theta[t] * DEG2RAD;
    const float c = cosf(th), s = sinf(th);
    const float s181 = s * 181.0f, c181 = c * 181.0f;

    const int   j  = jb * 32 + wj * 16 + jl;   // phantom j >= 363 ok
    const float xj = fmaf((float)j, STEP, -1.0f);
    const float bx = fmaf(c,  xj, 1.0f) * 181.0f;
    const float by = fmaf(-s, xj, 1.0f) * 181.0f;

    const int lane2 = lane * 2;
    const float fiofs = (float)(kk * 6);

    // ---- per-pair uniforms (case identical across the subtiles) ----
    const int tb = (tg * NJB + jb) * NIB + z * 4;
    const int caseA = (__builtin_amdgcn_readfirstlane(bbox[tb].z) >> 9) & 1;
    const f32x2* __restrict__ srcC = caseA ? xIc : xTIc;

    const float slopeU = caseA ? c181 : s181;
    const float slopeV = caseA ? s181 : c181;
    const float dU = slopeU * STEP;
    const float dV = slopeV * STEP;
    const float U00 = (caseA ? by : bx) - slopeU;
    const float V00 = (caseA ? bx : by) - slopeV;

    f32x2 acc0 = {0.0f, 0.0f}, acc1 = {0.0f, 0.0f};
    const int ib0 = z * 4;

    for (int ibi = 0; ibi < 4; ++ibi) {
        const int ib = ib0 + ibi;
        const int4 bb = bbox[tb + ibi];
        const int r0p    = __builtin_amdgcn_readfirstlane(bb.x);
        const int c0p    = __builtin_amdgcn_readfirstlane(bb.y);
        const int flags  = __builtin_amdgcn_readfirstlane(bb.z);
        const int nbase  = __builtin_amdgcn_readfirstlane(bb.w);
        const int nchunk = flags & 255;
        const int safe   = (flags >> 8) & 1;

        __syncthreads();                   // previous tile fully consumed

        if (safe) stage_direct<true >(tile, srcC, r0p, c0p, nchunk, wid, lane2);
        else      stage_direct<false>(tile, srcC, r0p, c0p, nchunk, wid, lane2);
        __syncthreads();                   // drains vmcnt -> tile ready

        // ---- gather: 6 samples/lane, incremental U/V walk ----
        const int i0 = ib * 24;
        const float fi = (float)i0 + fiofs;
        const float Uf = fmaf(dU, fi, U00);
        const float Vf = fmaf(dV, fi, V00);
        const int ibase = i0 + kk * 6;

        if (i0 + 23 < G) {                 // block-uniform
            gather6<false>(tile, Uf, Vf, dU, dV, nbase, 6, acc0, acc1);
        } else {
            gather6<true>(tile, Uf, Vf, dU, dV, nbase, G - ibase, acc0, acc1);
        }
    }

    // ---- reduce i-groups (lanes jl, jl+16, jl+32, jl+48) via shfl ----
    f32x2 v = acc0 + acc1;
    v.x += __shfl_xor(v.x, 16);
    v.y += __shfl_xor(v.y, 16);
    v.x += __shfl_xor(v.x, 32);
    v.y += __shfl_xor(v.y, 32);

    if (lane < 16 && j < G) {
        atomicAdd(&out[j * NT + t],          v.x);   // n = 0
        atomicAdd(&out[G * NT + j * NT + t], v.y);   // n = 1
    }
}

extern "C" void kernel_launch(void* const* d_in, const int* in_sizes, int n_in,
                              void* d_out, int out_size, void* d_ws, size_t ws_size,
                              hipStream_t stream) {
    const float* x     = (const float*)d_in[0];
    const int*   theta = (const int*)d_in[1];
    float*       out   = (float*)d_out;

    const size_t XIC_OFF  = 0;
    const size_t XTIC_OFF = (size_t)CH * CW * 8;                 // 544,960
    const size_t BBOX_OFF = 2 * XTIC_OFF;                        // 1,089,920
    const size_t NEED     = BBOX_OFF + (size_t)NTUPLE * 16;      // ~1.30 MiB

    if (ws_size < NEED) {   // fallback: known-good gather kernel
        hipLaunchKernelGGL(radon_fwd, dim3(NT * NJBF), dim3(64, 4), 0, stream,
                           x, theta, out);
        return;
    }

    f32x2* xIc  = (f32x2*)((char*)d_ws + XIC_OFF);
    f32x2* xTIc = (f32x2*)((char*)d_ws + XTIC_OFF);
    int4*  bbox = (int4*)((char*)d_ws + BBOX_OFF);

    hipLaunchKernelGGL(prep_k, dim3(277), dim3(32, 8), 0, stream,
                       x, theta, xIc, xTIc, bbox, out);
    hipLaunchKernelGGL(radon_tile4, dim3(1080, 4), dim3(256), 0, stream,
                       xIc, xTIc, theta, bbox, out);
}